// Round 5
// baseline (639.023 us; speedup 1.0000x reference)
//
#include <hip/hip_runtime.h>
#include <stdint.h>

#define BB 8
#define SS 2048
#define EE 512
#define INV_SCALE 0.04419417382415922f  // 1/sqrt(512)

typedef __attribute__((ext_vector_type(8))) short bf8_t;   // 8 bf16 in 4 VGPRs
typedef __attribute__((ext_vector_type(4))) float f4_t;    // MFMA accumulator

__device__ __forceinline__ unsigned short f2bf(float f) {
    union { float f; uint32_t u; } x; x.f = f;
    uint32_t r = x.u + 0x7fffu + ((x.u >> 16) & 1u);  // RNE
    return (unsigned short)(r >> 16);
}

// ---------------- prep kernels ----------------

__global__ void __launch_bounds__(256) gather_k_kernel(const int* __restrict__ idx,
                                                       const float* __restrict__ emb,
                                                       unsigned short* __restrict__ out) {
    int id = blockIdx.x * 256 + threadIdx.x;   // B*S*(E/8)
    int chunk = id & 63;
    int row = id >> 6;
    int e0 = chunk * 8;
    int k = idx[row];
    const float* src = emb + (size_t)k * EE + e0;
    float4 a = *(const float4*)(src);
    float4 c = *(const float4*)(src + 4);
    union { unsigned short s[8]; int4 v; } u;
    u.s[0] = f2bf(a.x); u.s[1] = f2bf(a.y); u.s[2] = f2bf(a.z); u.s[3] = f2bf(a.w);
    u.s[4] = f2bf(c.x); u.s[5] = f2bf(c.y); u.s[6] = f2bf(c.z); u.s[7] = f2bf(c.w);
    *(int4*)(out + (size_t)row * EE + e0) = u.v;
}

__global__ void __launch_bounds__(256) cast_h_kernel(const float* __restrict__ in,
                                                     unsigned short* __restrict__ out) {
    int id = blockIdx.x * 256 + threadIdx.x;
    const float* src = in + (size_t)id * 8;
    float4 a = *(const float4*)(src);
    float4 c = *(const float4*)(src + 4);
    union { unsigned short s[8]; int4 v; } u;
    u.s[0] = f2bf(a.x); u.s[1] = f2bf(a.y); u.s[2] = f2bf(a.z); u.s[3] = f2bf(a.w);
    u.s[4] = f2bf(c.x); u.s[5] = f2bf(c.y); u.s[6] = f2bf(c.z); u.s[7] = f2bf(c.w);
    *(int4*)(out + (size_t)id * 8) = u.v;
}

__global__ void __launch_bounds__(256) gather_vt_kernel(const int* __restrict__ idx,
                                                        const float* __restrict__ emb,
                                                        unsigned short* __restrict__ vt) {
    int id = blockIdx.x * 256 + threadIdx.x;   // B*E*S/8
    int t8 = id & 255;
    int rest = id >> 8;
    int e = rest & (EE - 1);
    int b = rest >> 9;
    int t0 = t8 * 8;
    const int* ip = idx + b * SS + t0;
    int4 i0 = *(const int4*)(ip);
    int4 i1 = *(const int4*)(ip + 4);
    union { unsigned short s[8]; int4 v; } u;
    u.s[0] = f2bf(emb[(size_t)i0.x * EE + e]);
    u.s[1] = f2bf(emb[(size_t)i0.y * EE + e]);
    u.s[2] = f2bf(emb[(size_t)i0.z * EE + e]);
    u.s[3] = f2bf(emb[(size_t)i0.w * EE + e]);
    u.s[4] = f2bf(emb[(size_t)i1.x * EE + e]);
    u.s[5] = f2bf(emb[(size_t)i1.y * EE + e]);
    u.s[6] = f2bf(emb[(size_t)i1.z * EE + e]);
    u.s[7] = f2bf(emb[(size_t)i1.w * EE + e]);
    *(int4*)(vt + ((size_t)b * EE + e) * SS + t0) = u.v;
}

__global__ void __launch_bounds__(256) transpose_w_kernel(const float* __restrict__ w,
                                                          unsigned short* __restrict__ wt) {
    int id = blockIdx.x * 256 + threadIdx.x;
    int e = id & (EE - 1);
    int f = id >> 9;
    wt[id] = f2bf(w[(size_t)e * EE + f] * INV_SCALE);
}

// ---------------- barrier-free per-wave pipelined GEMM core ----------------
// Workgroup = 1 wave. 64x64 tile, BK=32, quad-buffered private LDS (32 KB),
// prefetch distance 3, manual vmcnt waits. NO __syncthreads anywhere.
// LDS chunk-major: addr(row, kchunk) = kchunk*512 + row*8 shorts -> conflict-free b128 reads,
// staging dest = wave-uniform base + lane*16B (global_load_lds requirement).

#define WAITV16() asm volatile("s_waitcnt vmcnt(16)" ::: "memory")
#define WAITV8()  asm volatile("s_waitcnt vmcnt(8)"  ::: "memory")
#define WAITV0()  asm volatile("s_waitcnt vmcnt(0)"  ::: "memory")
#define MEMORDER() asm volatile("" ::: "memory")

// 8 global_load_lds per lane: A 64x32 + B 64x32 (4 KB each), chunk-major.
__device__ __forceinline__ void stageAB(const unsigned short* Ab, int lda,
                                        const unsigned short* Bb, int ldb, int k0,
                                        unsigned short* dA, unsigned short* dB, int lane) {
#pragma unroll
    for (int p = 0; p < 4; ++p) {
        const unsigned short* g = Ab + (size_t)lane * lda + k0 + p * 8;
        __builtin_amdgcn_global_load_lds((const __attribute__((address_space(1))) unsigned int*)g,
            (__attribute__((address_space(3))) unsigned int*)(dA + p * 512 + lane * 8), 16, 0, 0);
    }
#pragma unroll
    for (int p = 0; p < 4; ++p) {
        const unsigned short* g = Bb + (size_t)lane * ldb + k0 + p * 8;
        __builtin_amdgcn_global_load_lds((const __attribute__((address_space(1))) unsigned int*)g,
            (__attribute__((address_space(3))) unsigned int*)(dB + p * 512 + lane * 8), 16, 0, 0);
    }
}

__device__ __forceinline__ void read_frags(const unsigned short* sA, const unsigned short* sB,
                                           bf8_t af[4], bf8_t bf[4], int quad, int l16) {
#pragma unroll
    for (int mi = 0; mi < 4; ++mi)
        af[mi] = *(const bf8_t*)(sA + quad * 512 + (mi * 16 + l16) * 8);
#pragma unroll
    for (int ni = 0; ni < 4; ++ni)
        bf[ni] = *(const bf8_t*)(sB + quad * 512 + (ni * 16 + l16) * 8);
}

__device__ __forceinline__ void do_mfma(const bf8_t af[4], const bf8_t bf[4], f4_t acc[4][4]) {
#pragma unroll
    for (int mi = 0; mi < 4; ++mi)
#pragma unroll
        for (int ni = 0; ni < 4; ++ni)
            acc[mi][ni] = __builtin_amdgcn_mfma_f32_16x16x32_bf16(af[mi], bf[ni],
                                                                  acc[mi][ni], 0, 0, 0);
}

template <int NIT>
__device__ __forceinline__ void wave_gemm(const unsigned short* Ab, int lda,
                                          const unsigned short* Bb, int ldb,
                                          unsigned short (*sA)[2048], unsigned short (*sB)[2048],
                                          f4_t acc[4][4], int lane, int quad, int l16) {
    stageAB(Ab, lda, Bb, ldb, 0,  sA[0], sB[0], lane);
    stageAB(Ab, lda, Bb, ldb, 32, sA[1], sB[1], lane);
    stageAB(Ab, lda, Bb, ldb, 64, sA[2], sB[2], lane);
    bf8_t af[4], bf[4];
#pragma unroll 1
    for (int it = 0; it < NIT - 3; ++it) {
        WAITV16();                               // drain iter it; it+1, it+2 stay in flight
        int buf = it & 3;
        read_frags(sA[buf], sB[buf], af, bf, quad, l16);
        stageAB(Ab, lda, Bb, ldb, (it + 3) * 32, sA[(it + 3) & 3], sB[(it + 3) & 3], lane);
        do_mfma(af, bf, acc);                    // compiler inserts lgkm waits
    }
    // tail: NIT-3, NIT-2, NIT-1 (no more staging)
    WAITV16();
    read_frags(sA[(NIT - 3) & 3], sB[(NIT - 3) & 3], af, bf, quad, l16);
    do_mfma(af, bf, acc);
    WAITV8();
    read_frags(sA[(NIT - 2) & 3], sB[(NIT - 2) & 3], af, bf, quad, l16);
    do_mfma(af, bf, acc);
    WAITV0();
    read_frags(sA[(NIT - 1) & 3], sB[(NIT - 1) & 3], af, bf, quad, l16);
    do_mfma(af, bf, acc);
}

// ---------------- GEMM kernels (one wave per block) ----------------

// Q[s][f] = sum_e H[s][e] * Wt[f][e]  (scale folded into Wt), bf16 out
__global__ void __launch_bounds__(64) qgen_kernel(const unsigned short* __restrict__ H,
                                                  const unsigned short* __restrict__ Wt,
                                                  unsigned short* __restrict__ Q) {
    __shared__ __align__(16) unsigned short sA[4][2048];
    __shared__ __align__(16) unsigned short sB[4][2048];
    const int lane = threadIdx.x, quad = lane >> 4, l16 = lane & 15;
    const int mT = blockIdx.x, fT = blockIdx.y;   // 256 x 8
    f4_t acc[4][4];
    const f4_t z = {0.f, 0.f, 0.f, 0.f};
    for (int i = 0; i < 4; ++i) for (int j = 0; j < 4; ++j) acc[i][j] = z;
    wave_gemm<16>(H + (size_t)mT * 64 * EE, EE, Wt + (size_t)fT * 64 * EE, EE,
                  sA, sB, acc, lane, quad, l16);
#pragma unroll
    for (int mi = 0; mi < 4; ++mi)
#pragma unroll
        for (int r = 0; r < 4; ++r) {
            int row = mT * 64 + mi * 16 + quad * 4 + r;
#pragma unroll
            for (int ni = 0; ni < 4; ++ni) {
                int col = fT * 64 + ni * 16 + l16;
                Q[(size_t)row * EE + col] = f2bf(acc[mi][ni][r]);
            }
        }
}

// delta[b][s][t] = exp(Q.K) * clip(mask,0,1), bf16; lsum[b][s] += row partial sums
// grid.x = qT -> all 32 tT-sharers of a Q-strip land on XCD qT%8 (L2 co-location)
__global__ void __launch_bounds__(64) qk_kernel(const unsigned short* __restrict__ Q,
                                                const unsigned short* __restrict__ K,
                                                const float* __restrict__ mask,
                                                unsigned short* __restrict__ delta,
                                                float* __restrict__ lsum) {
    __shared__ __align__(16) unsigned short sA[4][2048];
    __shared__ __align__(16) unsigned short sB[4][2048];
    const int lane = threadIdx.x, quad = lane >> 4, l16 = lane & 15;
    const int qT = blockIdx.x, tT = blockIdx.y, b = blockIdx.z;  // 32 x 32 x 8
    f4_t acc[4][4];
    const f4_t z = {0.f, 0.f, 0.f, 0.f};
    for (int i = 0; i < 4; ++i) for (int j = 0; j < 4; ++j) acc[i][j] = z;
    wave_gemm<16>(Q + ((size_t)b * SS + qT * 64) * EE, EE,
                  K + ((size_t)b * SS + tT * 64) * EE, EE,
                  sA, sB, acc, lane, quad, l16);
#pragma unroll
    for (int mi = 0; mi < 4; ++mi)
#pragma unroll
        for (int r = 0; r < 4; ++r) {
            int rloc = mi * 16 + quad * 4 + r;
            int row = qT * 64 + rloc;
            const float* mrow = mask + ((size_t)b * SS + row) * SS + tT * 64;
            unsigned short* drow = delta + ((size_t)b * SS + row) * SS + tT * 64;
            float mv[4];
#pragma unroll
            for (int ni = 0; ni < 4; ++ni)
                mv[ni] = mrow[ni * 16 + l16];
            float psum = 0.f;
#pragma unroll
            for (int ni = 0; ni < 4; ++ni) {
                float m = fminf(fmaxf(mv[ni], 0.f), 1.f);
                float e = __expf(acc[mi][ni][r]) * m;
                drow[ni * 16 + l16] = f2bf(e);
                psum += e;
            }
#pragma unroll
            for (int off = 1; off < 16; off <<= 1)
                psum += __shfl_xor(psum, off, 16);
            if (l16 == 0) atomicAdd(&lsum[b * SS + row], psum);
        }
}

// out[b][s][e] = (sum_t delta[b][s][t] * Vt[b][e][t]) / (lsum[b][s] + 1e-10), fp32
// grid.x = qT -> 8 eT-sharers of each delta-strip co-locate per XCD
__global__ void __launch_bounds__(64) pv_kernel(const unsigned short* __restrict__ delta,
                                                const unsigned short* __restrict__ Vt,
                                                const float* __restrict__ lsum,
                                                float* __restrict__ out) {
    __shared__ __align__(16) unsigned short sA[4][2048];
    __shared__ __align__(16) unsigned short sB[4][2048];
    const int lane = threadIdx.x, quad = lane >> 4, l16 = lane & 15;
    const int qT = blockIdx.x, eT = blockIdx.y, b = blockIdx.z;  // 32 x 8 x 8
    // lsum prefetch: issued BEFORE staging so they are the oldest vmcnt entries
    float lv[4][4];
#pragma unroll
    for (int mi = 0; mi < 4; ++mi)
#pragma unroll
        for (int r = 0; r < 4; ++r)
            lv[mi][r] = lsum[b * SS + qT * 64 + mi * 16 + quad * 4 + r];
    MEMORDER();  // keep lsum loads older than all staging loads (vmcnt counting)
    f4_t acc[4][4];
    const f4_t z = {0.f, 0.f, 0.f, 0.f};
    for (int i = 0; i < 4; ++i) for (int j = 0; j < 4; ++j) acc[i][j] = z;
    wave_gemm<64>(delta + ((size_t)b * SS + qT * 64) * SS, SS,
                  Vt + ((size_t)b * EE + eT * 64) * SS, SS,
                  sA, sB, acc, lane, quad, l16);
#pragma unroll
    for (int mi = 0; mi < 4; ++mi)
#pragma unroll
        for (int r = 0; r < 4; ++r) {
            int row = qT * 64 + mi * 16 + quad * 4 + r;
            float iv = 1.0f / (lv[mi][r] + 1e-10f);
#pragma unroll
            for (int ni = 0; ni < 4; ++ni) {
                int col = eT * 64 + ni * 16 + l16;
                out[((size_t)b * SS + row) * EE + col] = acc[mi][ni][r] * iv;
            }
        }
}

// ---------------- launcher ----------------

extern "C" void kernel_launch(void* const* d_in, const int* in_sizes, int n_in,
                              void* d_out, int out_size, void* d_ws, size_t ws_size,
                              hipStream_t stream) {
    const int*   key_seq = (const int*)d_in[0];
    const int*   val_seq = (const int*)d_in[1];
    const float* hidden  = (const float*)d_in[2];
    const float* mask    = (const float*)d_in[3];
    // d_in[4] nan_matrix: unused by forward
    const float* key_emb = (const float*)d_in[5];
    const float* val_emb = (const float*)d_in[6];
    const float* weight  = (const float*)d_in[7];
    float* out = (float*)d_out;

    char* ws = (char*)d_ws;
    const size_t SZ_BSE = (size_t)BB * SS * EE * sizeof(unsigned short);  // 16,777,216
    unsigned short* Q    = (unsigned short*)(ws);
    unsigned short* K    = (unsigned short*)(ws + SZ_BSE);
    unsigned short* Vt   = (unsigned short*)(ws + 2 * SZ_BSE);
    unsigned short* H    = (unsigned short*)(ws + 3 * SZ_BSE);
    unsigned short* Wt   = (unsigned short*)(ws + 4 * SZ_BSE);            // 524,288 B
    float*          lsum = (float*)(ws + 4 * SZ_BSE + 524288);           // 65,536 B
    unsigned short* delta= (unsigned short*)(ws + 4 * SZ_BSE + 524288 + 65536); // 67,108,864 B

    hipMemsetAsync(lsum, 0, (size_t)BB * SS * sizeof(float), stream);

    gather_k_kernel<<<4096, 256, 0, stream>>>(key_seq, key_emb, K);
    cast_h_kernel<<<4096, 256, 0, stream>>>(hidden, H);
    gather_vt_kernel<<<4096, 256, 0, stream>>>(val_seq, val_emb, Vt);
    transpose_w_kernel<<<1024, 256, 0, stream>>>(weight, Wt);

    qgen_kernel<<<dim3(256, 8), 64, 0, stream>>>(H, Wt, Q);
    qk_kernel<<<dim3(32, 32, 8), 64, 0, stream>>>(Q, K, mask, delta, lsum);
    pv_kernel<<<dim3(32, 8, 8), 64, 0, stream>>>(delta, Vt, lsum, out);
}

// Round 6
// 493.899 us; speedup vs baseline: 1.2938x; 1.2938x over previous
//
#include <hip/hip_runtime.h>
#include <stdint.h>

#define BB 8
#define SS 2048
#define EE 512
#define INV_SCALE 0.04419417382415922f  // 1/sqrt(512)

typedef __attribute__((ext_vector_type(8))) short bf8_t;   // 8 bf16 in 4 VGPRs
typedef __attribute__((ext_vector_type(4))) float f4_t;    // MFMA accumulator

__device__ __forceinline__ unsigned short f2bf(float f) {
    union { float f; uint32_t u; } x; x.f = f;
    uint32_t r = x.u + 0x7fffu + ((x.u >> 16) & 1u);  // RNE
    return (unsigned short)(r >> 16);
}

// ---------------- prep kernels ----------------

__global__ void __launch_bounds__(256) gather_k_kernel(const int* __restrict__ idx,
                                                       const float* __restrict__ emb,
                                                       unsigned short* __restrict__ out) {
    int id = blockIdx.x * 256 + threadIdx.x;   // B*S*(E/8)
    int chunk = id & 63;
    int row = id >> 6;
    int e0 = chunk * 8;
    int k = idx[row];
    const float* src = emb + (size_t)k * EE + e0;
    float4 a = *(const float4*)(src);
    float4 c = *(const float4*)(src + 4);
    union { unsigned short s[8]; int4 v; } u;
    u.s[0] = f2bf(a.x); u.s[1] = f2bf(a.y); u.s[2] = f2bf(a.z); u.s[3] = f2bf(a.w);
    u.s[4] = f2bf(c.x); u.s[5] = f2bf(c.y); u.s[6] = f2bf(c.z); u.s[7] = f2bf(c.w);
    *(int4*)(out + (size_t)row * EE + e0) = u.v;
}

__global__ void __launch_bounds__(256) cast_h_kernel(const float* __restrict__ in,
                                                     unsigned short* __restrict__ out) {
    int id = blockIdx.x * 256 + threadIdx.x;
    const float* src = in + (size_t)id * 8;
    float4 a = *(const float4*)(src);
    float4 c = *(const float4*)(src + 4);
    union { unsigned short s[8]; int4 v; } u;
    u.s[0] = f2bf(a.x); u.s[1] = f2bf(a.y); u.s[2] = f2bf(a.z); u.s[3] = f2bf(a.w);
    u.s[4] = f2bf(c.x); u.s[5] = f2bf(c.y); u.s[6] = f2bf(c.z); u.s[7] = f2bf(c.w);
    *(int4*)(out + (size_t)id * 8) = u.v;
}

// Vt_bf16[b][e][t]; one thread = 8 consecutive t for fixed (b,e)
__global__ void __launch_bounds__(256) gather_vt_kernel(const int* __restrict__ idx,
                                                        const float* __restrict__ emb,
                                                        unsigned short* __restrict__ vt) {
    int id = blockIdx.x * 256 + threadIdx.x;   // B*E*S/8
    int t8 = id & 255;
    int rest = id >> 8;
    int e = rest & (EE - 1);
    int b = rest >> 9;
    int t0 = t8 * 8;
    const int* ip = idx + b * SS + t0;
    int4 i0 = *(const int4*)(ip);
    int4 i1 = *(const int4*)(ip + 4);
    union { unsigned short s[8]; int4 v; } u;
    u.s[0] = f2bf(emb[(size_t)i0.x * EE + e]);
    u.s[1] = f2bf(emb[(size_t)i0.y * EE + e]);
    u.s[2] = f2bf(emb[(size_t)i0.z * EE + e]);
    u.s[3] = f2bf(emb[(size_t)i0.w * EE + e]);
    u.s[4] = f2bf(emb[(size_t)i1.x * EE + e]);
    u.s[5] = f2bf(emb[(size_t)i1.y * EE + e]);
    u.s[6] = f2bf(emb[(size_t)i1.z * EE + e]);
    u.s[7] = f2bf(emb[(size_t)i1.w * EE + e]);
    *(int4*)(vt + ((size_t)b * EE + e) * SS + t0) = u.v;
}

__global__ void __launch_bounds__(256) transpose_w_kernel(const float* __restrict__ w,
                                                          unsigned short* __restrict__ wt) {
    int id = blockIdx.x * 256 + threadIdx.x;
    int e = id & (EE - 1);
    int f = id >> 9;
    wt[id] = f2bf(w[(size_t)e * EE + f] * INV_SCALE);
}

// ---------------- MFMA tile machinery: 128x128 tile, BK=64, chunk-major LDS ----------------
// 256 threads = 4 waves (2x2), wave tile 64x64 = 4x4 of 16x16, acc = 64 AGPR.
// LDS tile: addr(row, kc) = kc*2048B + row*16B (kc = 8-elem k-chunk, 8 chunks) -> 16 KB/tile.
//   staging combo c = p*4+wave in [0,16): kc=c>>1, half=c&1, row=half*64+lane
//     dest = kc*2048 + half*1024 + lane*16  (wave-uniform base + lane*16B as required)
//   fragment read: 16 consecutive rows x 16B at fixed kc = 256B contiguous -> conflict-free
//     (measured round 5: SQ_LDS_BANK_CONFLICT == 0 with this layout)

__device__ __forceinline__ void stage_bk64(const unsigned short* gbase, int ld, int k0,
                                           unsigned short* lds, int wave, int lane) {
#pragma unroll
    for (int p = 0; p < 4; ++p) {
        int c = p * 4 + wave;
        int kc = c >> 1, half = c & 1;
        const unsigned short* g = gbase + (size_t)(half * 64 + lane) * ld + k0 + kc * 8;
        unsigned short* l = lds + kc * 1024 + half * 512 + lane * 8;
        __builtin_amdgcn_global_load_lds((const __attribute__((address_space(1))) unsigned int*)g,
                                         (__attribute__((address_space(3))) unsigned int*)l,
                                         16, 0, 0);
    }
}

template <int KLEN>
__device__ __forceinline__ void mfma_loop64(const unsigned short* Abase, int lda,
                                            const unsigned short* Bbase, int ldb,
                                            unsigned short* As, unsigned short* Bs,
                                            f4_t acc[4][4], int wave, int lane) {
    const int wm = wave >> 1, wn = wave & 1;
    const int quad = lane >> 4, l16 = lane & 15;
#pragma unroll 1
    for (int k0 = 0; k0 < KLEN; k0 += 64) {
        stage_bk64(Abase, lda, k0, As, wave, lane);
        stage_bk64(Bbase, ldb, k0, Bs, wave, lane);
        __syncthreads();
#pragma unroll
        for (int kk = 0; kk < 2; ++kk) {
            bf8_t af[4], bfr[4];
#pragma unroll
            for (int mi = 0; mi < 4; ++mi)
                af[mi] = *(const bf8_t*)(As + ((kk * 4 + quad) * 128 + wm * 64 + mi * 16 + l16) * 8);
#pragma unroll
            for (int ni = 0; ni < 4; ++ni)
                bfr[ni] = *(const bf8_t*)(Bs + ((kk * 4 + quad) * 128 + wn * 64 + ni * 16 + l16) * 8);
#pragma unroll
            for (int mi = 0; mi < 4; ++mi)
#pragma unroll
                for (int ni = 0; ni < 4; ++ni)
                    acc[mi][ni] = __builtin_amdgcn_mfma_f32_16x16x32_bf16(af[mi], bfr[ni],
                                                                          acc[mi][ni], 0, 0, 0);
        }
        __syncthreads();
    }
}

// ---------------- GEMM kernels ----------------
// __launch_bounds__(256, 3): 3 waves/SIMD min -> total regs <= ~170; AGPR=64 => VGPR cap ~106.
// Round 1 ran 2 waves/SIMD (140 total regs); this buys +50% TLP for latency hiding.

__global__ void __launch_bounds__(256, 3) qgen_kernel(const unsigned short* __restrict__ H,
                                                      const unsigned short* __restrict__ Wt,
                                                      unsigned short* __restrict__ Q) {
    __shared__ __align__(16) unsigned short As[128 * 64];
    __shared__ __align__(16) unsigned short Bs[128 * 64];
    const int tid = threadIdx.x, wave = tid >> 6, lane = tid & 63;
    const int rowT = blockIdx.y, colT = blockIdx.x;  // 128 x 4
    f4_t acc[4][4];
    const f4_t z = {0.f, 0.f, 0.f, 0.f};
    for (int i = 0; i < 4; ++i) for (int j = 0; j < 4; ++j) acc[i][j] = z;
    mfma_loop64<EE>(H + (size_t)rowT * 128 * EE, EE,
                    Wt + (size_t)colT * 128 * EE, EE, As, Bs, acc, wave, lane);
    const int wm = wave >> 1, wn = wave & 1, quad = lane >> 4, l16 = lane & 15;
#pragma unroll
    for (int mi = 0; mi < 4; ++mi)
#pragma unroll
        for (int r = 0; r < 4; ++r) {
            int row = rowT * 128 + wm * 64 + mi * 16 + quad * 4 + r;
#pragma unroll
            for (int ni = 0; ni < 4; ++ni) {
                int col = colT * 128 + wn * 64 + ni * 16 + l16;
                Q[(size_t)row * EE + col] = f2bf(acc[mi][ni][r]);
            }
        }
}

// delta = exp(QK)*clip(mask), bf16; lsum row sums via one atomic per row-fragment.
// grid.x = tT -> all 16 qT-blocks sharing a K-strip land on XCD tT%8.
__global__ void __launch_bounds__(256, 3) qk_kernel(const unsigned short* __restrict__ Q,
                                                    const unsigned short* __restrict__ K,
                                                    const float* __restrict__ mask,
                                                    unsigned short* __restrict__ delta,
                                                    float* __restrict__ lsum) {
    __shared__ __align__(16) unsigned short As[128 * 64];
    __shared__ __align__(16) unsigned short Bs[128 * 64];
    const int tid = threadIdx.x, wave = tid >> 6, lane = tid & 63;
    const int b = blockIdx.z, qT = blockIdx.y, tT = blockIdx.x;
    const int wm = wave >> 1, wn = wave & 1, quad = lane >> 4, l16 = lane & 15;

    f4_t acc[4][4];
    const f4_t z = {0.f, 0.f, 0.f, 0.f};
    for (int i = 0; i < 4; ++i) for (int j = 0; j < 4; ++j) acc[i][j] = z;
    mfma_loop64<EE>(Q + ((size_t)b * SS + qT * 128) * EE, EE,
                    K + ((size_t)b * SS + tT * 128) * EE, EE, As, Bs, acc, wave, lane);

#pragma unroll
    for (int mi = 0; mi < 4; ++mi)
#pragma unroll
        for (int r = 0; r < 4; ++r) {
            int row = qT * 128 + wm * 64 + mi * 16 + quad * 4 + r;
            const float* mrow = mask + ((size_t)b * SS + row) * SS + tT * 128;
            unsigned short* drow = delta + ((size_t)b * SS + row) * SS + tT * 128;
            float mv[4];
#pragma unroll
            for (int ni = 0; ni < 4; ++ni)
                mv[ni] = mrow[wn * 64 + ni * 16 + l16];
            float psum = 0.f;
#pragma unroll
            for (int ni = 0; ni < 4; ++ni) {
                float m = fminf(fmaxf(mv[ni], 0.f), 1.f);
                float e = __expf(acc[mi][ni][r]) * m;
                drow[wn * 64 + ni * 16 + l16] = f2bf(e);
                psum += e;
            }
#pragma unroll
            for (int off = 1; off < 16; off <<= 1)
                psum += __shfl_xor(psum, off, 16);
            if (l16 == 0) atomicAdd(&lsum[b * SS + row], psum);
        }
}

// out = (delta @ Vt^T-ish) / (lsum + 1e-10), fp32.
// grid.x = qT -> the 4 eT-blocks sharing one freshly-written delta-strip co-locate on XCD qT%8.
__global__ void __launch_bounds__(256, 3) pv_kernel(const unsigned short* __restrict__ delta,
                                                    const unsigned short* __restrict__ Vt,
                                                    const float* __restrict__ lsum,
                                                    float* __restrict__ out) {
    __shared__ __align__(16) unsigned short As[128 * 64];
    __shared__ __align__(16) unsigned short Bs[128 * 64];
    const int tid = threadIdx.x, wave = tid >> 6, lane = tid & 63;
    const int b = blockIdx.z, eT = blockIdx.y, qT = blockIdx.x;
    const int wm = wave >> 1, wn = wave & 1, quad = lane >> 4, l16 = lane & 15;

    // lsum prefetch (independent of GEMM)
    float lv[4][4];
#pragma unroll
    for (int mi = 0; mi < 4; ++mi)
#pragma unroll
        for (int r = 0; r < 4; ++r)
            lv[mi][r] = lsum[b * SS + qT * 128 + wm * 64 + mi * 16 + quad * 4 + r];

    f4_t acc[4][4];
    const f4_t z = {0.f, 0.f, 0.f, 0.f};
    for (int i = 0; i < 4; ++i) for (int j = 0; j < 4; ++j) acc[i][j] = z;
    mfma_loop64<SS>(delta + ((size_t)b * SS + qT * 128) * SS, SS,
                    Vt + ((size_t)b * EE + eT * 128) * SS, SS, As, Bs, acc, wave, lane);

#pragma unroll
    for (int mi = 0; mi < 4; ++mi)
#pragma unroll
        for (int r = 0; r < 4; ++r) {
            int row = qT * 128 + wm * 64 + mi * 16 + quad * 4 + r;
            float iv = 1.0f / (lv[mi][r] + 1e-10f);
#pragma unroll
            for (int ni = 0; ni < 4; ++ni) {
                int col = eT * 128 + wn * 64 + ni * 16 + l16;
                out[((size_t)b * SS + row) * EE + col] = acc[mi][ni][r] * iv;
            }
        }
}

// ---------------- launcher ----------------

extern "C" void kernel_launch(void* const* d_in, const int* in_sizes, int n_in,
                              void* d_out, int out_size, void* d_ws, size_t ws_size,
                              hipStream_t stream) {
    const int*   key_seq = (const int*)d_in[0];
    const int*   val_seq = (const int*)d_in[1];
    const float* hidden  = (const float*)d_in[2];
    const float* mask    = (const float*)d_in[3];
    // d_in[4] nan_matrix: unused by forward
    const float* key_emb = (const float*)d_in[5];
    const float* val_emb = (const float*)d_in[6];
    const float* weight  = (const float*)d_in[7];
    float* out = (float*)d_out;

    char* ws = (char*)d_ws;
    const size_t SZ_BSE = (size_t)BB * SS * EE * sizeof(unsigned short);  // 16,777,216
    unsigned short* Q    = (unsigned short*)(ws);
    unsigned short* K    = (unsigned short*)(ws + SZ_BSE);
    unsigned short* Vt   = (unsigned short*)(ws + 2 * SZ_BSE);
    unsigned short* H    = (unsigned short*)(ws + 3 * SZ_BSE);
    unsigned short* Wt   = (unsigned short*)(ws + 4 * SZ_BSE);            // 524,288 B
    float*          lsum = (float*)(ws + 4 * SZ_BSE + 524288);           // 65,536 B
    unsigned short* delta= (unsigned short*)(ws + 4 * SZ_BSE + 524288 + 65536); // 67,108,864 B

    hipMemsetAsync(lsum, 0, (size_t)BB * SS * sizeof(float), stream);

    gather_k_kernel<<<4096, 256, 0, stream>>>(key_seq, key_emb, K);
    cast_h_kernel<<<4096, 256, 0, stream>>>(hidden, H);
    gather_vt_kernel<<<4096, 256, 0, stream>>>(val_seq, val_emb, Vt);
    transpose_w_kernel<<<1024, 256, 0, stream>>>(weight, Wt);

    qgen_kernel<<<dim3(4, 128), 256, 0, stream>>>(H, Wt, Q);
    qk_kernel<<<dim3(16, 16, 8), 256, 0, stream>>>(Q, K, mask, delta, lsum);
    pv_kernel<<<dim3(16, 4, 8), 256, 0, stream>>>(delta, Vt, lsum, out);
}